// Round 4
// baseline (140.170 us; speedup 1.0000x reference)
//
#include <hip/hip_runtime.h>
#include <hip/hip_bf16.h>
#include <math.h>

#define N_RAYS   32768
#define N_SAMP   1048576
#define HID      64
#define ITERS    4
#define BLK_HALF 1024               // per net: 1024 blk * 4 waves * 4 iters * 64 = 1,048,576
#define BLK_A    (2*BLK_HALF)       // blocks interleaved by XCD-pairing (R15)

typedef short bf8 __attribute__((ext_vector_type(8)));   // 8 x bf16 bits
typedef short bf4 __attribute__((ext_vector_type(4)));   // 4 x bf16 bits
typedef float f4  __attribute__((ext_vector_type(4)));

union BF8U { bf8 v; unsigned u[4]; };
union BF4U { bf4 v; unsigned u[2]; };

// Layer-1 only has K=4 real data; K=16 MFMA when available (R14 keep):
// a1 is 8 VGPRs, xb 2. Same C/D layout as the x32 op.
#if __has_builtin(__builtin_amdgcn_mfma_f32_16x16x16bf16_1k)
#define HAVE_M16 1
#else
#define HAVE_M16 0
#endif

// f32->bf16 pair pack via the C++ cast: the compiler fuses cast pairs into
// v_cvt_pk_bf16_f32 on gfx950. DO NOT replace with manual bit-twiddled RNE —
// R6 measured it 45% SLOWER (defeats the fusion; VALU-busy cyc 79k->101k).
static __device__ __forceinline__ unsigned bfbits(float x) {
    union { __bf16 h; unsigned short s; } c; c.h = (__bf16)x; return (unsigned)c.s;
}
static __device__ __forceinline__ unsigned pk2(float a, float b) {
#if __has_builtin(__builtin_amdgcn_cvt_pk_bf16_f32)
    return __builtin_bit_cast(unsigned, __builtin_amdgcn_cvt_pk_bf16_f32(a, b));
#else
    return bfbits(a) | (bfbits(b) << 16);
#endif
}
// R15: relu AFTER the pack. bf16 is sign-magnitude, so v_pk_max_i16 with 0
// zeroes exactly the negative halves (incl. -0.0 -> +0). pk2r drops from
// 3 VALU ops (fmax,fmax,cvt_pk) to 2 (cvt_pk,pk_max) — 64 calls/it.
static __device__ __forceinline__ unsigned relu_pk(unsigned u) {
    unsigned r;
    asm("v_pk_max_i16 %0, %1, 0" : "=v"(r) : "v"(u));
    return r;
}
static __device__ __forceinline__ unsigned pk2r(float a, float b) {
    return relu_pk(pk2(a, b));
}
static __device__ __forceinline__ f4 mfma16(bf8 a, bf8 b, f4 c) {
    return __builtin_amdgcn_mfma_f32_16x16x32_bf16(a, b, c, 0, 0, 0);
}

// Fragment buffer layout (per net): 14 uint4 slots x 64 lanes (a1[0..3],
// a2[t*2+s -> 4..11], a3[12..13]) then 5 float4 slots x 64 lanes (bias2[0..3],
// bias3[4] — slot 4 unused by pass_a, kept for layout compat).
#define FRAG_SLOTS 14
#define BIAS_SLOTS 5

// ---------------------------------------------------------------------------
// Prep (R14): parallelized 16x — one thread per (net,lane,job), 8 blocks x 256.
// jobs 0..7  : A2 slot (2t+s)      (8 loads)
// jobs 8..11 : A1 slot t + bias2 t (8 loads)
// jobs 12,13 : A3 slot s           (8 loads)
// job  14    : bias3               (3 loads)
// ---------------------------------------------------------------------------
__global__ __launch_bounds__(256) void prep_frags(
    const float* __restrict__ Wd1, const float* __restrict__ bd1,
    const float* __restrict__ Wd2, const float* __restrict__ bd2,
    const float* __restrict__ Wd3, const float* __restrict__ bd3,
    const float* __restrict__ Wr1, const float* __restrict__ br1,
    const float* __restrict__ Wr2, const float* __restrict__ br2,
    const float* __restrict__ Wr3, const float* __restrict__ br3,
    uint4* __restrict__ fragbuf, float4* __restrict__ biasbuf)
{
    const int g = blockIdx.x * blockDim.x + threadIdx.x;
    if (g >= 2048) return;
    const int net  = g >> 10;          // 0 = density, 1 = rgb
    const int job  = (g >> 6) & 15;
    const int lane = g & 63;
    const int q    = lane >> 4;
    const int n    = lane & 15;
    const int qn   = n >> 2, rn = n & 3;
    const int rt   = n & 3;

    const float* W1 = net ? Wr1 : Wd1;  const float* b1 = net ? br1 : bd1;
    const float* W2 = net ? Wr2 : Wd2;  const float* b2 = net ? br2 : bd2;
    const float* W3 = net ? Wr3 : Wd3;  const float* b3 = net ? br3 : bd3;
    const int    nc = net ? 3 : 1;
    const int    ch = net ? (rt < 3 ? rt : 2) : 0;

    uint4*  fb = fragbuf + net * (FRAG_SLOTS * 64);
    float4* bb = biasbuf + net * (BIAS_SLOTS * 64);

    if (job < 8) {
        // A2 slot = 4 + job   (job = 2t + s)
        const int t = job >> 1, s = job & 1;
        const int row = 8*qn + 4*(t&1) + rn + 32*(t>>1);
        unsigned u[4];
        #pragma unroll
        for (int dw = 0; dw < 4; ++dw) {
            const int k = 8*q + 2*dw + 32*s;
            u[dw] = pk2(W2[k*HID+row], W2[(k+1)*HID+row]);
        }
        fb[(4 + job)*64 + lane] = make_uint4(u[0], u[1], u[2], u[3]);
    } else if (job < 12) {
        // A1 slot t + bias2 slot t
        const int t = job - 8;
        const int row = 8*qn + 4*(t&1) + rn + 32*(t>>1);
        uint4 f;
        f.x = pk2(W1[row],       W1[HID+row]);
        f.y = pk2(W1[2*HID+row], b1[row]);
        f.z = 0u; f.w = 0u;
        fb[t*64 + lane] = f;

        const int base = 8*q + 4*(t&1) + 32*(t>>1);
        float4 g4;
        g4.x = b2[base + 0];
        g4.y = b2[base + 1];
        g4.z = b2[base + 2];
        g4.w = b2[base + 3];
        bb[t*64 + lane] = g4;
    } else if (job < 14) {
        // A3 slot 12+s
        const int s = job - 12;
        unsigned u[4];
        #pragma unroll
        for (int dw = 0; dw < 4; ++dw) {
            const int kg = 32*s + 8*q + 2*dw;
            u[dw] = pk2(W3[kg*nc + ch], W3[(kg+1)*nc + ch]);
        }
        fb[(12 + s)*64 + lane] = make_uint4(u[0], u[1], u[2], u[3]);
    } else if (job == 14) {
        // bias3 slot (layout compat; pass_a reads b3 via SGPRs)
        float4 f;
        f.x = b3[0];
        f.y = net ? b3[1] : b3[0];
        f.z = net ? b3[2] : b3[0];
        f.w = net ? b3[2] : b3[0];
        bb[4*64 + lane] = f;
    }
}

// ---------------------------------------------------------------------------
// Pass A: SPLIT BY NET (R7) + PRE-PACKED FRAGMENTS (R10) + XCD pairing (R15).
// R16 post-mortem: (256,2) produced NaN — codegen artifact at the 256-reg
// budget; the experiment was invalid, not a falsification. (256,2) is
// POISONED — do not retry. Reverted to (256,3).
// R17 theory: occupancy 31% = ~3 waves/SIMD on a 512-reg/SIMD pool => true
// footprint ~170 = 60 arch VGPR + ~110 AGPR. Semantic live set is only ~140,
// so the compiler is software-pipelining the unrolled u-loop, inflating the
// live set, parking overlap values in AGPRs, and paying v_accvgpr copies on
// every pk2/bias access (measured ~975 VALU/wave-iter vs ~210 semantic).
// R17: #pragma unroll 1 on the u-loop — kills cross-u pipelining, live set
// fits arch VGPRs, copies vanish. ILP loss is covered by 3 resident waves
// (issue was 84% busy; TLP carries throughput, not ILP).
// Spill tripwire: FETCH_SIZE must stay ~7.8 MB (R4: scratch spill -> 852 MB).
// ---------------------------------------------------------------------------
__global__ __launch_bounds__(256, 3) void pass_a(
    const float* __restrict__ rays_o, const float* __restrict__ rays_d,
    const float* __restrict__ t_starts, const float* __restrict__ t_ends,
    const int*   __restrict__ ray_idx,
    const uint4* __restrict__ fragbuf, const float4* __restrict__ biasbuf,
    const float* __restrict__ bd3, const float* __restrict__ br3,
    float4* __restrict__ ws4, float* __restrict__ ws_mid,
    int* __restrict__ start)
{
    // R15 XCD pairing: b and b+8 process the SAME sample range for the two
    // nets; round-robin XCD assignment (b%8) puts them on the same XCD/L2.
    const int  b      = blockIdx.x;
    const bool is_rgb = (b >> 3) & 1;
    const int  blk    = (b & 7) | ((b >> 4) << 3);     // 0..BLK_HALF-1 per net
    const int  lane   = threadIdx.x & 63;
    const int  wv     = ((blk << 8) + threadIdx.x) >> 6;   // 0..4095 per net
    const int  q      = lane >> 4;

    const uint4*  fb = fragbuf + (is_rgb ? FRAG_SLOTS*64 : 0);
    const float4* bb = biasbuf + (is_rgb ? BIAS_SLOTS*64 : 0);

#if HAVE_M16
    bf4 a1[4];
    {
        const uint2* fb2 = (const uint2*)fb;
        #pragma unroll
        for (int t = 0; t < 4; ++t) {
            const uint2 w = fb2[(t*64 + lane)*2];   // low 8B of the uint4 slot
            BF4U c; c.u[0] = w.x; c.u[1] = w.y;
            a1[t] = c.v;
        }
    }
#else
    bf8 a1[4];
    #pragma unroll
    for (int t = 0; t < 4; ++t)
        a1[t] = __builtin_bit_cast(bf8, fb[t*64 + lane]);
#endif
    bf8 a2[4][2];
    #pragma unroll
    for (int t = 0; t < 4; ++t)
        #pragma unroll
        for (int s = 0; s < 2; ++s)
            a2[t][s] = __builtin_bit_cast(bf8, fb[(4 + 2*t + s)*64 + lane]);
    bf8 a3[2];
    #pragma unroll
    for (int s = 0; s < 2; ++s)
        a3[s] = __builtin_bit_cast(bf8, fb[(12 + s)*64 + lane]);
    f4 bias2[4];
    #pragma unroll
    for (int t = 0; t < 4; ++t)
        bias2[t] = __builtin_bit_cast(f4, bb[t*64 + lane]);

    // bias3 via uniform scalar loads (SGPRs)
    const float* b3 = is_rgb ? br3 : bd3;
    const float b30 = b3[0];
    const float b31 = is_rgb ? b3[1] : b30;
    const float b32 = is_rgb ? b3[2] : b30;

    const int base0 = wv * (ITERS * 64);

    #pragma unroll 1
    for (int it = 0; it < ITERS; ++it) {
        const int smp = base0 + it * 64 + lane;

        const float ts = t_starts[smp], te = t_ends[smp];
        const int   ri = ray_idx[smp];
        const float mid = 0.5f*(ts+te), dt = te - ts;
        const float px = rays_o[3*ri+0] + rays_d[3*ri+0]*mid;
        const float py = rays_o[3*ri+1] + rays_d[3*ri+1]*mid;
        const float pz = rays_o[3*ri+2] + rays_d[3*ri+2]*mid;
        const unsigned p01 = pk2(px, py);
        const unsigned p23 = pk2(pz, 1.0f);

        if (!is_rgb) {
            // segment boundaries (density half only)
            int rp = __shfl_up(ri, 1, 64);
            if (lane == 0) rp = (smp == 0) ? -1 : ray_idx[smp-1];
            for (int rr = rp + 1; rr <= ri; ++rr) start[rr] = smp;
            if (smp == N_SAMP - 1)
                for (int rr = ri + 1; rr <= N_RAYS; ++rr) start[rr] = N_SAMP;
        }

        f4 mine = {0.f, 0.f, 0.f, 0.f};

        // R17: unroll 1 — see header comment. Dynamic u costs ~5 extra VALU
        // per pass (cmp+cndmask) but collapses the pipelined live set.
        #pragma unroll 1
        for (int u = 0; u < 4; ++u) {
            const f4 zero = {0.f, 0.f, 0.f, 0.f};
            f4 d1[4];
#if HAVE_M16
            BF4U xb;
            xb.u[0] = (q == u) ? p01 : 0u;
            xb.u[1] = (q == u) ? p23 : 0u;
            #pragma unroll
            for (int t = 0; t < 4; ++t)
                d1[t] = __builtin_amdgcn_mfma_f32_16x16x16bf16_1k(a1[t], xb.v, zero, 0, 0, 0);
#else
            BF8U xb;
            xb.u[0] = (q == u) ? p01 : 0u;
            xb.u[1] = (q == u) ? p23 : 0u;
            xb.u[2] = 0u; xb.u[3] = 0u;
            #pragma unroll
            for (int t = 0; t < 4; ++t) d1[t] = mfma16(a1[t], xb.v, zero);
#endif

            bf8 bf2[2];
            #pragma unroll
            for (int s = 0; s < 2; ++s) {
                BF8U p;
                p.u[0] = pk2r(d1[2*s][0],   d1[2*s][1]);
                p.u[1] = pk2r(d1[2*s][2],   d1[2*s][3]);
                p.u[2] = pk2r(d1[2*s+1][0], d1[2*s+1][1]);
                p.u[3] = pk2r(d1[2*s+1][2], d1[2*s+1][3]);
                bf2[s] = p.v;
            }

            f4 d2[4];
            #pragma unroll
            for (int t = 0; t < 4; ++t) {
                f4 a = bias2[t];
                a = mfma16(a2[t][0], bf2[0], a);
                a = mfma16(a2[t][1], bf2[1], a);
                d2[t] = a;
            }

            bf8 bf3[2];
            #pragma unroll
            for (int s = 0; s < 2; ++s) {
                BF8U p;
                p.u[0] = pk2r(d2[2*s][0],   d2[2*s][1]);
                p.u[1] = pk2r(d2[2*s][2],   d2[2*s][3]);
                p.u[2] = pk2r(d2[2*s+1][0], d2[2*s+1][1]);
                p.u[3] = pk2r(d2[2*s+1][2], d2[2*s+1][3]);
                bf3[s] = p.v;
            }

            f4 c3 = {b30, b31, b32, b32};
            c3 = mfma16(a3[0], bf3[0], c3);
            c3 = mfma16(a3[1], bf3[1], c3);

            if (q == u) mine = c3;   // lane's own sample's outputs
        }

        // full-width epilogue: byte-disjoint partial stores into ws4[smp]
        float* w4 = (float*)(ws4 + smp);
        if (!is_rgb) {
            const float sg = mine[0];
            const float sp = fmaxf(sg, 0.f) + __logf(1.f + __expf(-fabsf(sg)));
            w4[3] = sp * dt;            // .w = sigma_dt
            ws_mid[smp] = mid;          // mid plane (saves pass_b two loads)
        } else {
            w4[0] = __builtin_amdgcn_rcpf(1.f + __expf(-mine[0]));
            w4[1] = __builtin_amdgcn_rcpf(1.f + __expf(-mine[1]));
            w4[2] = __builtin_amdgcn_rcpf(1.f + __expf(-mine[2]));
        }
    }
}

// ---------------------------------------------------------------------------
// Pass B: TWO rays per wave (32 lanes each). Telescoping weights
// w = exp(-excl) - exp(-incl); per-chunk closed-form opacity (no reduce).
// R13: 2 loads per sample (float4 + mid) instead of 6 — shorter VMEM chain.
// start[] clamped: rocprof dispatch-replay can hand this kernel re-poisoned
// (0xAA) workspace -> unguarded loop ran 41ms under profiling (R4).
// ---------------------------------------------------------------------------
__global__ __launch_bounds__(256) void pass_b(
    const float4* __restrict__ ws4, const float* __restrict__ ws_mid,
    const int* __restrict__ start, float* __restrict__ out)
{
    const int lane = threadIdx.x & 63;
    const int wv   = (blockIdx.x * blockDim.x + threadIdx.x) >> 6;
    const int half = lane >> 5;
    const int l32  = lane & 31;
    const int r    = 2*wv + half;
    if (r >= N_RAYS) return;

    int s0 = start[r], s1 = start[r+1];
    s0 = min(max(s0, 0), N_SAMP);
    s1 = min(max(s1, s0), N_SAMP);

    float cum = 0.f, opac = 0.f, dist = 0.f, c0 = 0.f, c1 = 0.f, c2 = 0.f;

    for (int base = s0; base < s1; base += 32) {
        int s = base + l32;
        bool ok = s < s1;
        float4 v  = ok ? ws4[s]    : make_float4(0.f, 0.f, 0.f, 0.f);
        float mid = ok ? ws_mid[s] : 0.f;
        float sd  = v.w;

        float x = sd;                       // inclusive scan over 32 lanes
        #pragma unroll
        for (int off = 1; off < 32; off <<= 1) {
            float y = __shfl_up(x, off, 32);
            if (l32 >= off) x += y;
        }
        float incl = cum + x;
        float excl = incl - sd;
        float w = __expf(-excl) - __expf(-incl);   // trans*alpha, telescoped
        dist += w*mid; c0 += w*v.x; c1 += w*v.y; c2 += w*v.z;

        float tot = __shfl(x, 31, 32);
        opac += __expf(-cum) - __expf(-(cum + tot));  // uniform across lanes
        cum  += tot;
    }

    #pragma unroll
    for (int off = 16; off > 0; off >>= 1) {
        dist += __shfl_xor(dist, off, 32);
        c0   += __shfl_xor(c0,   off, 32);
        c1   += __shfl_xor(c1,   off, 32);
        c2   += __shfl_xor(c2,   off, 32);
    }

    if (l32 == 0) {
        float rest = 1.f - opac;
        out[r*3 + 0] = c0 + 0.5f * rest;
        out[r*3 + 1] = c1 + 0.5f * rest;
        out[r*3 + 2] = c2 + 0.5f * rest;
        out[3*N_RAYS + r] = dist + 5.f * rest;
        out[4*N_RAYS + r] = opac;
    }
}

extern "C" void kernel_launch(void* const* d_in, const int* in_sizes, int n_in,
                              void* d_out, int out_size, void* d_ws, size_t ws_size,
                              hipStream_t stream) {
    const float* rays_o   = (const float*)d_in[0];
    const float* rays_d   = (const float*)d_in[1];
    const float* t_starts = (const float*)d_in[2];
    const float* t_ends   = (const float*)d_in[3];
    const int*   ray_idx  = (const int*)  d_in[4];
    const float* Wd1 = (const float*)d_in[5];  const float* bd1 = (const float*)d_in[6];
    const float* Wd2 = (const float*)d_in[7];  const float* bd2 = (const float*)d_in[8];
    const float* Wd3 = (const float*)d_in[9];  const float* bd3 = (const float*)d_in[10];
    const float* Wr1 = (const float*)d_in[11]; const float* br1 = (const float*)d_in[12];
    const float* Wr2 = (const float*)d_in[13]; const float* br2 = (const float*)d_in[14];
    const float* Wr3 = (const float*)d_in[15]; const float* br3 = (const float*)d_in[16];

    float4* ws4    = (float4*)d_ws;                    // 16 MB AoS {r,g,b,sd}
    float*  ws_mid = (float*)(ws4 + N_SAMP);           // 4 MB mid plane
    char*   p      = (char*)(ws_mid + N_SAMP);
    int*    startb  = (int*)p;                         // (N_RAYS+1)*4 B
    uint4*  fragbuf = (uint4*)(p + (((N_RAYS+1)*4 + 255) & ~255));
    float4* biasbuf = (float4*)(fragbuf + 2*FRAG_SLOTS*64);
    float*  out     = (float*)d_out;

    hipLaunchKernelGGL(prep_frags, dim3(8), dim3(256), 0, stream,
                       Wd1, bd1, Wd2, bd2, Wd3, bd3,
                       Wr1, br1, Wr2, br2, Wr3, br3, fragbuf, biasbuf);

    hipLaunchKernelGGL(pass_a, dim3(BLK_A), dim3(256), 0, stream,
                       rays_o, rays_d, t_starts, t_ends, ray_idx,
                       fragbuf, biasbuf, bd3, br3, ws4, ws_mid, startb);

    hipLaunchKernelGGL(pass_b, dim3((N_RAYS/2 * 64) / 256), dim3(256), 0, stream,
                       ws4, ws_mid, startb, out);
}

// Round 7
// 139.334 us; speedup vs baseline: 1.0060x; 1.0060x over previous
//
#include <hip/hip_runtime.h>
#include <hip/hip_bf16.h>
#include <math.h>

#define N_RAYS   32768
#define N_SAMP   1048576
#define HID      64
#define ITERS    4
#define BLK_HALF 1024               // per net: 1024 blk * 4 waves * 4 iters * 64 = 1,048,576
#define BLK_A    (2*BLK_HALF)       // blocks interleaved by XCD-pairing (R15)

typedef short bf8 __attribute__((ext_vector_type(8)));   // 8 x bf16 bits
typedef short bf4 __attribute__((ext_vector_type(4)));   // 4 x bf16 bits
typedef float f4  __attribute__((ext_vector_type(4)));

union BF8U { bf8 v; unsigned u[4]; };
union BF4U { bf4 v; unsigned u[2]; };

// Layer-1 only has K=4 real data; K=16 MFMA when available (R14 keep):
// a1 is 8 VGPRs, xb 2. Same C/D layout as the x32 op.
#if __has_builtin(__builtin_amdgcn_mfma_f32_16x16x16bf16_1k)
#define HAVE_M16 1
#else
#define HAVE_M16 0
#endif

// f32->bf16 pair pack via the C++ cast: the compiler fuses cast pairs into
// v_cvt_pk_bf16_f32 on gfx950. DO NOT replace with manual bit-twiddled RNE —
// R6 measured it 45% SLOWER (defeats the fusion; VALU-busy cyc 79k->101k).
static __device__ __forceinline__ unsigned bfbits(float x) {
    union { __bf16 h; unsigned short s; } c; c.h = (__bf16)x; return (unsigned)c.s;
}
static __device__ __forceinline__ unsigned pk2(float a, float b) {
#if __has_builtin(__builtin_amdgcn_cvt_pk_bf16_f32)
    return __builtin_bit_cast(unsigned, __builtin_amdgcn_cvt_pk_bf16_f32(a, b));
#else
    return bfbits(a) | (bfbits(b) << 16);
#endif
}
// R15: relu AFTER the pack. bf16 is sign-magnitude, so v_pk_max_i16 with 0
// zeroes exactly the negative halves (incl. -0.0 -> +0). pk2r drops from
// 3 VALU ops (fmax,fmax,cvt_pk) to 2 (cvt_pk,pk_max) — 64 calls/it.
static __device__ __forceinline__ unsigned relu_pk(unsigned u) {
    unsigned r;
    asm("v_pk_max_i16 %0, %1, 0" : "=v"(r) : "v"(u));
    return r;
}
static __device__ __forceinline__ unsigned pk2r(float a, float b) {
    return relu_pk(pk2(a, b));
}
static __device__ __forceinline__ f4 mfma16(bf8 a, bf8 b, f4 c) {
    return __builtin_amdgcn_mfma_f32_16x16x32_bf16(a, b, c, 0, 0, 0);
}

// Fragment buffer layout (per net): 14 uint4 slots x 64 lanes (a1[0..3],
// a2[t*2+s -> 4..11], a3[12..13]) then 5 float4 slots x 64 lanes (bias2[0..3],
// bias3[4] — slot 4 unused by pass_a, kept for layout compat).
#define FRAG_SLOTS 14
#define BIAS_SLOTS 5

// ---------------------------------------------------------------------------
// Prep (R14): parallelized 16x — one thread per (net,lane,job), 8 blocks x 256.
// jobs 0..7  : A2 slot (2t+s)      (8 loads)
// jobs 8..11 : A1 slot t + bias2 t (8 loads)
// jobs 12,13 : A3 slot s           (8 loads)
// job  14    : bias3               (3 loads)
// ---------------------------------------------------------------------------
__global__ __launch_bounds__(256) void prep_frags(
    const float* __restrict__ Wd1, const float* __restrict__ bd1,
    const float* __restrict__ Wd2, const float* __restrict__ bd2,
    const float* __restrict__ Wd3, const float* __restrict__ bd3,
    const float* __restrict__ Wr1, const float* __restrict__ br1,
    const float* __restrict__ Wr2, const float* __restrict__ br2,
    const float* __restrict__ Wr3, const float* __restrict__ br3,
    uint4* __restrict__ fragbuf, float4* __restrict__ biasbuf)
{
    const int g = blockIdx.x * blockDim.x + threadIdx.x;
    if (g >= 2048) return;
    const int net  = g >> 10;          // 0 = density, 1 = rgb
    const int job  = (g >> 6) & 15;
    const int lane = g & 63;
    const int q    = lane >> 4;
    const int n    = lane & 15;
    const int qn   = n >> 2, rn = n & 3;
    const int rt   = n & 3;

    const float* W1 = net ? Wr1 : Wd1;  const float* b1 = net ? br1 : bd1;
    const float* W2 = net ? Wr2 : Wd2;  const float* b2 = net ? br2 : bd2;
    const float* W3 = net ? Wr3 : Wd3;  const float* b3 = net ? br3 : bd3;
    const int    nc = net ? 3 : 1;
    const int    ch = net ? (rt < 3 ? rt : 2) : 0;

    uint4*  fb = fragbuf + net * (FRAG_SLOTS * 64);
    float4* bb = biasbuf + net * (BIAS_SLOTS * 64);

    if (job < 8) {
        // A2 slot = 4 + job   (job = 2t + s)
        const int t = job >> 1, s = job & 1;
        const int row = 8*qn + 4*(t&1) + rn + 32*(t>>1);
        unsigned u[4];
        #pragma unroll
        for (int dw = 0; dw < 4; ++dw) {
            const int k = 8*q + 2*dw + 32*s;
            u[dw] = pk2(W2[k*HID+row], W2[(k+1)*HID+row]);
        }
        fb[(4 + job)*64 + lane] = make_uint4(u[0], u[1], u[2], u[3]);
    } else if (job < 12) {
        // A1 slot t + bias2 slot t
        const int t = job - 8;
        const int row = 8*qn + 4*(t&1) + rn + 32*(t>>1);
        uint4 f;
        f.x = pk2(W1[row],       W1[HID+row]);
        f.y = pk2(W1[2*HID+row], b1[row]);
        f.z = 0u; f.w = 0u;
        fb[t*64 + lane] = f;

        const int base = 8*q + 4*(t&1) + 32*(t>>1);
        float4 g4;
        g4.x = b2[base + 0];
        g4.y = b2[base + 1];
        g4.z = b2[base + 2];
        g4.w = b2[base + 3];
        bb[t*64 + lane] = g4;
    } else if (job < 14) {
        // A3 slot 12+s
        const int s = job - 12;
        unsigned u[4];
        #pragma unroll
        for (int dw = 0; dw < 4; ++dw) {
            const int kg = 32*s + 8*q + 2*dw;
            u[dw] = pk2(W3[kg*nc + ch], W3[(kg+1)*nc + ch]);
        }
        fb[(12 + s)*64 + lane] = make_uint4(u[0], u[1], u[2], u[3]);
    } else if (job == 14) {
        // bias3 slot (layout compat; pass_a reads b3 via SGPRs)
        float4 f;
        f.x = b3[0];
        f.y = net ? b3[1] : b3[0];
        f.z = net ? b3[2] : b3[0];
        f.w = net ? b3[2] : b3[0];
        bb[4*64 + lane] = f;
    }
}

// ---------------------------------------------------------------------------
// Pass A: SPLIT BY NET (R7) + PRE-PACKED FRAGMENTS (R10) + (256,3) (R11).
// R20 RE-ANCHOR: byte-identical to R15 (passed, 139.2 us total). R16
// ((256,2)), R18 (shared-record epilogue) and R19 (split-plane epilogue,
// no aliasing at all) ALL NaN'd with no deterministic mechanism found —
// this run distinguishes "those diffs were genuinely bad" from "harness
// flake". Do not change anything else in this round.
// Spill tripwire: FETCH_SIZE must stay ~7.8 MB (R4: spill -> 852 MB).
// ---------------------------------------------------------------------------
__global__ __launch_bounds__(256, 3) void pass_a(
    const float* __restrict__ rays_o, const float* __restrict__ rays_d,
    const float* __restrict__ t_starts, const float* __restrict__ t_ends,
    const int*   __restrict__ ray_idx,
    const uint4* __restrict__ fragbuf, const float4* __restrict__ biasbuf,
    const float* __restrict__ bd3, const float* __restrict__ br3,
    float4* __restrict__ ws4, float* __restrict__ ws_mid,
    int* __restrict__ start)
{
    // R15 XCD pairing: b and b+8 process the SAME sample range for the two
    // nets; round-robin XCD assignment (b%8) puts them on the same XCD/L2.
    const int  b      = blockIdx.x;
    const bool is_rgb = (b >> 3) & 1;
    const int  blk    = (b & 7) | ((b >> 4) << 3);     // 0..BLK_HALF-1 per net
    const int  lane   = threadIdx.x & 63;
    const int  wv     = ((blk << 8) + threadIdx.x) >> 6;   // 0..4095 per net
    const int  q      = lane >> 4;

    const uint4*  fb = fragbuf + (is_rgb ? FRAG_SLOTS*64 : 0);
    const float4* bb = biasbuf + (is_rgb ? BIAS_SLOTS*64 : 0);

#if HAVE_M16
    bf4 a1[4];
    {
        const uint2* fb2 = (const uint2*)fb;
        #pragma unroll
        for (int t = 0; t < 4; ++t) {
            const uint2 w = fb2[(t*64 + lane)*2];   // low 8B of the uint4 slot
            BF4U c; c.u[0] = w.x; c.u[1] = w.y;
            a1[t] = c.v;
        }
    }
#else
    bf8 a1[4];
    #pragma unroll
    for (int t = 0; t < 4; ++t)
        a1[t] = __builtin_bit_cast(bf8, fb[t*64 + lane]);
#endif
    bf8 a2[4][2];
    #pragma unroll
    for (int t = 0; t < 4; ++t)
        #pragma unroll
        for (int s = 0; s < 2; ++s)
            a2[t][s] = __builtin_bit_cast(bf8, fb[(4 + 2*t + s)*64 + lane]);
    bf8 a3[2];
    #pragma unroll
    for (int s = 0; s < 2; ++s)
        a3[s] = __builtin_bit_cast(bf8, fb[(12 + s)*64 + lane]);
    f4 bias2[4];
    #pragma unroll
    for (int t = 0; t < 4; ++t)
        bias2[t] = __builtin_bit_cast(f4, bb[t*64 + lane]);

    // bias3 via uniform scalar loads (SGPRs)
    const float* b3 = is_rgb ? br3 : bd3;
    const float b30 = b3[0];
    const float b31 = is_rgb ? b3[1] : b30;
    const float b32 = is_rgb ? b3[2] : b30;

    const int base0 = wv * (ITERS * 64);

    #pragma unroll 1
    for (int it = 0; it < ITERS; ++it) {
        const int smp = base0 + it * 64 + lane;

        const float ts = t_starts[smp], te = t_ends[smp];
        const int   ri = ray_idx[smp];
        const float mid = 0.5f*(ts+te), dt = te - ts;
        const float px = rays_o[3*ri+0] + rays_d[3*ri+0]*mid;
        const float py = rays_o[3*ri+1] + rays_d[3*ri+1]*mid;
        const float pz = rays_o[3*ri+2] + rays_d[3*ri+2]*mid;
        const unsigned p01 = pk2(px, py);
        const unsigned p23 = pk2(pz, 1.0f);

        if (!is_rgb) {
            // segment boundaries (density half only)
            int rp = __shfl_up(ri, 1, 64);
            if (lane == 0) rp = (smp == 0) ? -1 : ray_idx[smp-1];
            for (int rr = rp + 1; rr <= ri; ++rr) start[rr] = smp;
            if (smp == N_SAMP - 1)
                for (int rr = ri + 1; rr <= N_RAYS; ++rr) start[rr] = N_SAMP;
        }

        f4 mine = {0.f, 0.f, 0.f, 0.f};

        #pragma unroll
        for (int u = 0; u < 4; ++u) {
            const f4 zero = {0.f, 0.f, 0.f, 0.f};
            f4 d1[4];
#if HAVE_M16
            BF4U xb;
            xb.u[0] = (q == u) ? p01 : 0u;
            xb.u[1] = (q == u) ? p23 : 0u;
            #pragma unroll
            for (int t = 0; t < 4; ++t)
                d1[t] = __builtin_amdgcn_mfma_f32_16x16x16bf16_1k(a1[t], xb.v, zero, 0, 0, 0);
#else
            BF8U xb;
            xb.u[0] = (q == u) ? p01 : 0u;
            xb.u[1] = (q == u) ? p23 : 0u;
            xb.u[2] = 0u; xb.u[3] = 0u;
            #pragma unroll
            for (int t = 0; t < 4; ++t) d1[t] = mfma16(a1[t], xb.v, zero);
#endif

            bf8 bf2[2];
            #pragma unroll
            for (int s = 0; s < 2; ++s) {
                BF8U p;
                p.u[0] = pk2r(d1[2*s][0],   d1[2*s][1]);
                p.u[1] = pk2r(d1[2*s][2],   d1[2*s][3]);
                p.u[2] = pk2r(d1[2*s+1][0], d1[2*s+1][1]);
                p.u[3] = pk2r(d1[2*s+1][2], d1[2*s+1][3]);
                bf2[s] = p.v;
            }

            f4 d2[4];
            #pragma unroll
            for (int t = 0; t < 4; ++t) {
                f4 a = bias2[t];
                a = mfma16(a2[t][0], bf2[0], a);
                a = mfma16(a2[t][1], bf2[1], a);
                d2[t] = a;
            }

            bf8 bf3[2];
            #pragma unroll
            for (int s = 0; s < 2; ++s) {
                BF8U p;
                p.u[0] = pk2r(d2[2*s][0],   d2[2*s][1]);
                p.u[1] = pk2r(d2[2*s][2],   d2[2*s][3]);
                p.u[2] = pk2r(d2[2*s+1][0], d2[2*s+1][1]);
                p.u[3] = pk2r(d2[2*s+1][2], d2[2*s+1][3]);
                bf3[s] = p.v;
            }

            f4 c3 = {b30, b31, b32, b32};
            c3 = mfma16(a3[0], bf3[0], c3);
            c3 = mfma16(a3[1], bf3[1], c3);

            if (q == u) mine = c3;   // lane's own sample's outputs
        }

        // full-width epilogue: byte-disjoint partial stores into ws4[smp]
        float* w4 = (float*)(ws4 + smp);
        if (!is_rgb) {
            const float sg = mine[0];
            const float sp = fmaxf(sg, 0.f) + __logf(1.f + __expf(-fabsf(sg)));
            w4[3] = sp * dt;            // .w = sigma_dt
            ws_mid[smp] = mid;          // mid plane (saves pass_b two loads)
        } else {
            w4[0] = __builtin_amdgcn_rcpf(1.f + __expf(-mine[0]));
            w4[1] = __builtin_amdgcn_rcpf(1.f + __expf(-mine[1]));
            w4[2] = __builtin_amdgcn_rcpf(1.f + __expf(-mine[2]));
        }
    }
}

// ---------------------------------------------------------------------------
// Pass B: TWO rays per wave (32 lanes each). Telescoping weights
// w = exp(-excl) - exp(-incl); per-chunk closed-form opacity (no reduce).
// R13: 2 loads per sample (float4 + mid) instead of 6 — shorter VMEM chain.
// start[] clamped: rocprof dispatch-replay can hand this kernel re-poisoned
// (0xAA) workspace -> unguarded loop ran 41ms under profiling (R4).
// ---------------------------------------------------------------------------
__global__ __launch_bounds__(256) void pass_b(
    const float4* __restrict__ ws4, const float* __restrict__ ws_mid,
    const int* __restrict__ start, float* __restrict__ out)
{
    const int lane = threadIdx.x & 63;
    const int wv   = (blockIdx.x * blockDim.x + threadIdx.x) >> 6;
    const int half = lane >> 5;
    const int l32  = lane & 31;
    const int r    = 2*wv + half;
    if (r >= N_RAYS) return;

    int s0 = start[r], s1 = start[r+1];
    s0 = min(max(s0, 0), N_SAMP);
    s1 = min(max(s1, s0), N_SAMP);

    float cum = 0.f, opac = 0.f, dist = 0.f, c0 = 0.f, c1 = 0.f, c2 = 0.f;

    for (int base = s0; base < s1; base += 32) {
        int s = base + l32;
        bool ok = s < s1;
        float4 v  = ok ? ws4[s]    : make_float4(0.f, 0.f, 0.f, 0.f);
        float mid = ok ? ws_mid[s] : 0.f;
        float sd  = v.w;

        float x = sd;                       // inclusive scan over 32 lanes
        #pragma unroll
        for (int off = 1; off < 32; off <<= 1) {
            float y = __shfl_up(x, off, 32);
            if (l32 >= off) x += y;
        }
        float incl = cum + x;
        float excl = incl - sd;
        float w = __expf(-excl) - __expf(-incl);   // trans*alpha, telescoped
        dist += w*mid; c0 += w*v.x; c1 += w*v.y; c2 += w*v.z;

        float tot = __shfl(x, 31, 32);
        opac += __expf(-cum) - __expf(-(cum + tot));  // uniform across lanes
        cum  += tot;
    }

    #pragma unroll
    for (int off = 16; off > 0; off >>= 1) {
        dist += __shfl_xor(dist, off, 32);
        c0   += __shfl_xor(c0,   off, 32);
        c1   += __shfl_xor(c1,   off, 32);
        c2   += __shfl_xor(c2,   off, 32);
    }

    if (l32 == 0) {
        float rest = 1.f - opac;
        out[r*3 + 0] = c0 + 0.5f * rest;
        out[r*3 + 1] = c1 + 0.5f * rest;
        out[r*3 + 2] = c2 + 0.5f * rest;
        out[3*N_RAYS + r] = dist + 5.f * rest;
        out[4*N_RAYS + r] = opac;
    }
}

extern "C" void kernel_launch(void* const* d_in, const int* in_sizes, int n_in,
                              void* d_out, int out_size, void* d_ws, size_t ws_size,
                              hipStream_t stream) {
    const float* rays_o   = (const float*)d_in[0];
    const float* rays_d   = (const float*)d_in[1];
    const float* t_starts = (const float*)d_in[2];
    const float* t_ends   = (const float*)d_in[3];
    const int*   ray_idx  = (const int*)  d_in[4];
    const float* Wd1 = (const float*)d_in[5];  const float* bd1 = (const float*)d_in[6];
    const float* Wd2 = (const float*)d_in[7];  const float* bd2 = (const float*)d_in[8];
    const float* Wd3 = (const float*)d_in[9];  const float* bd3 = (const float*)d_in[10];
    const float* Wr1 = (const float*)d_in[11]; const float* br1 = (const float*)d_in[12];
    const float* Wr2 = (const float*)d_in[13]; const float* br2 = (const float*)d_in[14];
    const float* Wr3 = (const float*)d_in[15]; const float* br3 = (const float*)d_in[16];

    float4* ws4    = (float4*)d_ws;                    // 16 MB AoS {r,g,b,sd}
    float*  ws_mid = (float*)(ws4 + N_SAMP);           // 4 MB mid plane
    char*   p      = (char*)(ws_mid + N_SAMP);
    int*    startb  = (int*)p;                         // (N_RAYS+1)*4 B
    uint4*  fragbuf = (uint4*)(p + (((N_RAYS+1)*4 + 255) & ~255));
    float4* biasbuf = (float4*)(fragbuf + 2*FRAG_SLOTS*64);
    float*  out     = (float*)d_out;

    hipLaunchKernelGGL(prep_frags, dim3(8), dim3(256), 0, stream,
                       Wd1, bd1, Wd2, bd2, Wd3, bd3,
                       Wr1, br1, Wr2, br2, Wr3, br3, fragbuf, biasbuf);

    hipLaunchKernelGGL(pass_a, dim3(BLK_A), dim3(256), 0, stream,
                       rays_o, rays_d, t_starts, t_ends, ray_idx,
                       fragbuf, biasbuf, bd3, br3, ws4, ws_mid, startb);

    hipLaunchKernelGGL(pass_b, dim3((N_RAYS/2 * 64) / 256), dim3(256), 0, stream,
                       ws4, ws_mid, startb, out);
}

// Round 8
// 137.511 us; speedup vs baseline: 1.0193x; 1.0133x over previous
//
#include <hip/hip_runtime.h>
#include <hip/hip_bf16.h>
#include <math.h>

#define N_RAYS   32768
#define N_SAMP   1048576
#define HID      64
#define ITERS    4
#define BLK_HALF 1024               // per net: 1024 blk * 4 waves * 4 iters * 64 = 1,048,576
#define BLK_A    (2*BLK_HALF)       // blocks interleaved by XCD-pairing (R15)

typedef short bf8 __attribute__((ext_vector_type(8)));   // 8 x bf16 bits
typedef short bf4 __attribute__((ext_vector_type(4)));   // 4 x bf16 bits
typedef float f4  __attribute__((ext_vector_type(4)));

union BF8U { bf8 v; unsigned u[4]; };
union BF4U { bf4 v; unsigned u[2]; };

// Layer-1 only has K=4 real data; K=16 MFMA when available (R14 keep):
// a1 is 8 VGPRs, xb 2. Same C/D layout as the x32 op.
#if __has_builtin(__builtin_amdgcn_mfma_f32_16x16x16bf16_1k)
#define HAVE_M16 1
#else
#define HAVE_M16 0
#endif

// f32->bf16 pair pack via the C++ cast: the compiler fuses cast pairs into
// v_cvt_pk_bf16_f32 on gfx950. DO NOT replace with manual bit-twiddled RNE —
// R6 measured it 45% SLOWER (defeats the fusion; VALU-busy cyc 79k->101k).
static __device__ __forceinline__ unsigned bfbits(float x) {
    union { __bf16 h; unsigned short s; } c; c.h = (__bf16)x; return (unsigned)c.s;
}
static __device__ __forceinline__ unsigned pk2(float a, float b) {
#if __has_builtin(__builtin_amdgcn_cvt_pk_bf16_f32)
    return __builtin_bit_cast(unsigned, __builtin_amdgcn_cvt_pk_bf16_f32(a, b));
#else
    return bfbits(a) | (bfbits(b) << 16);
#endif
}
// R15: relu AFTER the pack. bf16 is sign-magnitude, so v_pk_max_i16 with 0
// zeroes exactly the negative halves (incl. -0.0 -> +0). pk2r drops from
// 3 VALU ops (fmax,fmax,cvt_pk) to 2 (cvt_pk,pk_max) — 64 calls/it.
static __device__ __forceinline__ unsigned relu_pk(unsigned u) {
    unsigned r;
    asm("v_pk_max_i16 %0, %1, 0" : "=v"(r) : "v"(u));
    return r;
}
static __device__ __forceinline__ unsigned pk2r(float a, float b) {
    return relu_pk(pk2(a, b));
}
static __device__ __forceinline__ f4 mfma16(bf8 a, bf8 b, f4 c) {
    return __builtin_amdgcn_mfma_f32_16x16x32_bf16(a, b, c, 0, 0, 0);
}

// Fragment buffer layout (per net): 14 uint4 slots x 64 lanes (a1[0..3],
// a2[t*2+s -> 4..11], a3[12..13]) then 5 float4 slots x 64 lanes (bias2[0..3],
// bias3[4] — slot 4 unused by pass_a, kept for layout compat).
#define FRAG_SLOTS 14
#define BIAS_SLOTS 5

// ---------------------------------------------------------------------------
// Prep (R14): parallelized 16x — one thread per (net,lane,job), 8 blocks x 256.
// jobs 0..7  : A2 slot (2t+s)      (8 loads)
// jobs 8..11 : A1 slot t + bias2 t (8 loads)
// jobs 12,13 : A3 slot s           (8 loads)
// job  14    : bias3               (3 loads)
// ---------------------------------------------------------------------------
__global__ __launch_bounds__(256) void prep_frags(
    const float* __restrict__ Wd1, const float* __restrict__ bd1,
    const float* __restrict__ Wd2, const float* __restrict__ bd2,
    const float* __restrict__ Wd3, const float* __restrict__ bd3,
    const float* __restrict__ Wr1, const float* __restrict__ br1,
    const float* __restrict__ Wr2, const float* __restrict__ br2,
    const float* __restrict__ Wr3, const float* __restrict__ br3,
    uint4* __restrict__ fragbuf, float4* __restrict__ biasbuf)
{
    const int g = blockIdx.x * blockDim.x + threadIdx.x;
    if (g >= 2048) return;
    const int net  = g >> 10;          // 0 = density, 1 = rgb
    const int job  = (g >> 6) & 15;
    const int lane = g & 63;
    const int q    = lane >> 4;
    const int n    = lane & 15;
    const int qn   = n >> 2, rn = n & 3;
    const int rt   = n & 3;

    const float* W1 = net ? Wr1 : Wd1;  const float* b1 = net ? br1 : bd1;
    const float* W2 = net ? Wr2 : Wd2;  const float* b2 = net ? br2 : bd2;
    const float* W3 = net ? Wr3 : Wd3;  const float* b3 = net ? br3 : bd3;
    const int    nc = net ? 3 : 1;
    const int    ch = net ? (rt < 3 ? rt : 2) : 0;

    uint4*  fb = fragbuf + net * (FRAG_SLOTS * 64);
    float4* bb = biasbuf + net * (BIAS_SLOTS * 64);

    if (job < 8) {
        // A2 slot = 4 + job   (job = 2t + s)
        const int t = job >> 1, s = job & 1;
        const int row = 8*qn + 4*(t&1) + rn + 32*(t>>1);
        unsigned u[4];
        #pragma unroll
        for (int dw = 0; dw < 4; ++dw) {
            const int k = 8*q + 2*dw + 32*s;
            u[dw] = pk2(W2[k*HID+row], W2[(k+1)*HID+row]);
        }
        fb[(4 + job)*64 + lane] = make_uint4(u[0], u[1], u[2], u[3]);
    } else if (job < 12) {
        // A1 slot t + bias2 slot t
        const int t = job - 8;
        const int row = 8*qn + 4*(t&1) + rn + 32*(t>>1);
        uint4 f;
        f.x = pk2(W1[row],       W1[HID+row]);
        f.y = pk2(W1[2*HID+row], b1[row]);
        f.z = 0u; f.w = 0u;
        fb[t*64 + lane] = f;

        const int base = 8*q + 4*(t&1) + 32*(t>>1);
        float4 g4;
        g4.x = b2[base + 0];
        g4.y = b2[base + 1];
        g4.z = b2[base + 2];
        g4.w = b2[base + 3];
        bb[t*64 + lane] = g4;
    } else if (job < 14) {
        // A3 slot 12+s
        const int s = job - 12;
        unsigned u[4];
        #pragma unroll
        for (int dw = 0; dw < 4; ++dw) {
            const int kg = 32*s + 8*q + 2*dw;
            u[dw] = pk2(W3[kg*nc + ch], W3[(kg+1)*nc + ch]);
        }
        fb[(12 + s)*64 + lane] = make_uint4(u[0], u[1], u[2], u[3]);
    } else if (job == 14) {
        // bias3 slot (layout compat; pass_a reads b3 via SGPRs)
        float4 f;
        f.x = b3[0];
        f.y = net ? b3[1] : b3[0];
        f.z = net ? b3[2] : b3[0];
        f.w = net ? b3[2] : b3[0];
        bb[4*64 + lane] = f;
    }
}

// ---------------------------------------------------------------------------
// Pass A: SPLIT BY NET (R7) + PRE-PACKED FRAGMENTS (R10) + XCD pairing (R15).
// R20 re-anchor PASSED (139.3 us == R15's 139.2): harness is deterministic;
// R16/R18/R19 NaNs were real consequences of those diffs. FROZEN territory:
// the epilogue/store layout (3/3 NaNs when touched) and (256,2).
// R21 theory: pass_a is latency-bound at ~3 waves/SIMD; cap = total unified
// register footprint (~56 arch VGPR + ~110 AGPR ~ 168/wave). R14's (256,4)
// was ignored because the live set couldn't fit 128. Fix the LIVE SET:
// move a2 (32 regs) + bias2 (16 regs) to LDS — stage 12 KB once per block
// (slots are contiguous in fragbuf/biasbuf), ds_read_b128 per use. LDS pipe
// cost ~0.6 us/wave hides under the 75%-idle VALU/MFMA pipes. Live ~120
// -> (256,4) honorable -> 4 waves/SIMD.
// Predicted: Occupancy 29.7 -> ~40-45, dur 43 -> ~31-35. Falsifier: flat
// occupancy => 43 us is the structural floor; revert next round.
// Spill tripwire: FETCH_SIZE must stay ~7-8 MB (R4: spill -> 852 MB).
// ---------------------------------------------------------------------------
__global__ __launch_bounds__(256, 4) void pass_a(
    const float* __restrict__ rays_o, const float* __restrict__ rays_d,
    const float* __restrict__ t_starts, const float* __restrict__ t_ends,
    const int*   __restrict__ ray_idx,
    const uint4* __restrict__ fragbuf, const float4* __restrict__ biasbuf,
    const float* __restrict__ bd3, const float* __restrict__ br3,
    float4* __restrict__ ws4, float* __restrict__ ws_mid,
    int* __restrict__ start)
{
    // R15 XCD pairing: b and b+8 process the SAME sample range for the two
    // nets; round-robin XCD assignment (b%8) puts them on the same XCD/L2.
    const int  b      = blockIdx.x;
    const bool is_rgb = (b >> 3) & 1;
    const int  blk    = (b & 7) | ((b >> 4) << 3);     // 0..BLK_HALF-1 per net
    const int  lane   = threadIdx.x & 63;
    const int  wv     = ((blk << 8) + threadIdx.x) >> 6;   // 0..4095 per net
    const int  q      = lane >> 4;

    const uint4*  fb = fragbuf + (is_rgb ? FRAG_SLOTS*64 : 0);
    const float4* bb = biasbuf + (is_rgb ? BIAS_SLOTS*64 : 0);

    // R21: a2 slots 4..11 (8 x 64 uint4 = 8 KB) + bias2 slots 0..3 (4 KB)
    // staged in LDS; all waves of the block read the same 12 KB.
    __shared__ uint4  lds_a2[8 * 64];
    __shared__ float4 lds_b2[4 * 64];
    for (int i = threadIdx.x; i < 8 * 64; i += 256)
        lds_a2[i] = fb[4 * 64 + i];          // slots 4..11 are contiguous
    for (int i = threadIdx.x; i < 4 * 64; i += 256)
        lds_b2[i] = bb[i];                   // slots 0..3 are contiguous
    __syncthreads();

#if HAVE_M16
    bf4 a1[4];
    {
        const uint2* fb2 = (const uint2*)fb;
        #pragma unroll
        for (int t = 0; t < 4; ++t) {
            const uint2 w = fb2[(t*64 + lane)*2];   // low 8B of the uint4 slot
            BF4U c; c.u[0] = w.x; c.u[1] = w.y;
            a1[t] = c.v;
        }
    }
#else
    bf8 a1[4];
    #pragma unroll
    for (int t = 0; t < 4; ++t)
        a1[t] = __builtin_bit_cast(bf8, fb[t*64 + lane]);
#endif
    bf8 a3[2];
    #pragma unroll
    for (int s = 0; s < 2; ++s)
        a3[s] = __builtin_bit_cast(bf8, fb[(12 + s)*64 + lane]);

    // bias3 via uniform scalar loads (SGPRs)
    const float* b3 = is_rgb ? br3 : bd3;
    const float b30 = b3[0];
    const float b31 = is_rgb ? b3[1] : b30;
    const float b32 = is_rgb ? b3[2] : b30;

    const int base0 = wv * (ITERS * 64);

    #pragma unroll 1
    for (int it = 0; it < ITERS; ++it) {
        const int smp = base0 + it * 64 + lane;

        const float ts = t_starts[smp], te = t_ends[smp];
        const int   ri = ray_idx[smp];
        const float mid = 0.5f*(ts+te), dt = te - ts;
        const float px = rays_o[3*ri+0] + rays_d[3*ri+0]*mid;
        const float py = rays_o[3*ri+1] + rays_d[3*ri+1]*mid;
        const float pz = rays_o[3*ri+2] + rays_d[3*ri+2]*mid;
        const unsigned p01 = pk2(px, py);
        const unsigned p23 = pk2(pz, 1.0f);

        if (!is_rgb) {
            // segment boundaries (density half only)
            int rp = __shfl_up(ri, 1, 64);
            if (lane == 0) rp = (smp == 0) ? -1 : ray_idx[smp-1];
            for (int rr = rp + 1; rr <= ri; ++rr) start[rr] = smp;
            if (smp == N_SAMP - 1)
                for (int rr = ri + 1; rr <= N_RAYS; ++rr) start[rr] = N_SAMP;
        }

        f4 mine = {0.f, 0.f, 0.f, 0.f};

        #pragma unroll
        for (int u = 0; u < 4; ++u) {
            const f4 zero = {0.f, 0.f, 0.f, 0.f};
            f4 d1[4];
#if HAVE_M16
            BF4U xb;
            xb.u[0] = (q == u) ? p01 : 0u;
            xb.u[1] = (q == u) ? p23 : 0u;
            #pragma unroll
            for (int t = 0; t < 4; ++t)
                d1[t] = __builtin_amdgcn_mfma_f32_16x16x16bf16_1k(a1[t], xb.v, zero, 0, 0, 0);
#else
            BF8U xb;
            xb.u[0] = (q == u) ? p01 : 0u;
            xb.u[1] = (q == u) ? p23 : 0u;
            xb.u[2] = 0u; xb.u[3] = 0u;
            #pragma unroll
            for (int t = 0; t < 4; ++t) d1[t] = mfma16(a1[t], xb.v, zero);
#endif

            bf8 bf2[2];
            #pragma unroll
            for (int s = 0; s < 2; ++s) {
                BF8U p;
                p.u[0] = pk2r(d1[2*s][0],   d1[2*s][1]);
                p.u[1] = pk2r(d1[2*s][2],   d1[2*s][3]);
                p.u[2] = pk2r(d1[2*s+1][0], d1[2*s+1][1]);
                p.u[3] = pk2r(d1[2*s+1][2], d1[2*s+1][3]);
                bf2[s] = p.v;
            }

            f4 d2[4];
            #pragma unroll
            for (int t = 0; t < 4; ++t) {
                f4 a = __builtin_bit_cast(f4, lds_b2[t*64 + lane]);
                a = mfma16(__builtin_bit_cast(bf8, lds_a2[(2*t+0)*64 + lane]), bf2[0], a);
                a = mfma16(__builtin_bit_cast(bf8, lds_a2[(2*t+1)*64 + lane]), bf2[1], a);
                d2[t] = a;
            }

            bf8 bf3[2];
            #pragma unroll
            for (int s = 0; s < 2; ++s) {
                BF8U p;
                p.u[0] = pk2r(d2[2*s][0],   d2[2*s][1]);
                p.u[1] = pk2r(d2[2*s][2],   d2[2*s][3]);
                p.u[2] = pk2r(d2[2*s+1][0], d2[2*s+1][1]);
                p.u[3] = pk2r(d2[2*s+1][2], d2[2*s+1][3]);
                bf3[s] = p.v;
            }

            f4 c3 = {b30, b31, b32, b32};
            c3 = mfma16(a3[0], bf3[0], c3);
            c3 = mfma16(a3[1], bf3[1], c3);

            if (q == u) mine = c3;   // lane's own sample's outputs
        }

        // full-width epilogue: byte-disjoint partial stores into ws4[smp]
        // (FROZEN — do not restructure; R16/R18/R19 NaN'd when perturbed)
        float* w4 = (float*)(ws4 + smp);
        if (!is_rgb) {
            const float sg = mine[0];
            const float sp = fmaxf(sg, 0.f) + __logf(1.f + __expf(-fabsf(sg)));
            w4[3] = sp * dt;            // .w = sigma_dt
            ws_mid[smp] = mid;          // mid plane (saves pass_b two loads)
        } else {
            w4[0] = __builtin_amdgcn_rcpf(1.f + __expf(-mine[0]));
            w4[1] = __builtin_amdgcn_rcpf(1.f + __expf(-mine[1]));
            w4[2] = __builtin_amdgcn_rcpf(1.f + __expf(-mine[2]));
        }
    }
}

// ---------------------------------------------------------------------------
// Pass B: TWO rays per wave (32 lanes each). Telescoping weights
// w = exp(-excl) - exp(-incl); per-chunk closed-form opacity (no reduce).
// R13: 2 loads per sample (float4 + mid) instead of 6 — shorter VMEM chain.
// start[] clamped: rocprof dispatch-replay can hand this kernel re-poisoned
// (0xAA) workspace -> unguarded loop ran 41ms under profiling (R4).
// ---------------------------------------------------------------------------
__global__ __launch_bounds__(256) void pass_b(
    const float4* __restrict__ ws4, const float* __restrict__ ws_mid,
    const int* __restrict__ start, float* __restrict__ out)
{
    const int lane = threadIdx.x & 63;
    const int wv   = (blockIdx.x * blockDim.x + threadIdx.x) >> 6;
    const int half = lane >> 5;
    const int l32  = lane & 31;
    const int r    = 2*wv + half;
    if (r >= N_RAYS) return;

    int s0 = start[r], s1 = start[r+1];
    s0 = min(max(s0, 0), N_SAMP);
    s1 = min(max(s1, s0), N_SAMP);

    float cum = 0.f, opac = 0.f, dist = 0.f, c0 = 0.f, c1 = 0.f, c2 = 0.f;

    for (int base = s0; base < s1; base += 32) {
        int s = base + l32;
        bool ok = s < s1;
        float4 v  = ok ? ws4[s]    : make_float4(0.f, 0.f, 0.f, 0.f);
        float mid = ok ? ws_mid[s] : 0.f;
        float sd  = v.w;

        float x = sd;                       // inclusive scan over 32 lanes
        #pragma unroll
        for (int off = 1; off < 32; off <<= 1) {
            float y = __shfl_up(x, off, 32);
            if (l32 >= off) x += y;
        }
        float incl = cum + x;
        float excl = incl - sd;
        float w = __expf(-excl) - __expf(-incl);   // trans*alpha, telescoped
        dist += w*mid; c0 += w*v.x; c1 += w*v.y; c2 += w*v.z;

        float tot = __shfl(x, 31, 32);
        opac += __expf(-cum) - __expf(-(cum + tot));  // uniform across lanes
        cum  += tot;
    }

    #pragma unroll
    for (int off = 16; off > 0; off >>= 1) {
        dist += __shfl_xor(dist, off, 32);
        c0   += __shfl_xor(c0,   off, 32);
        c1   += __shfl_xor(c1,   off, 32);
        c2   += __shfl_xor(c2,   off, 32);
    }

    if (l32 == 0) {
        float rest = 1.f - opac;
        out[r*3 + 0] = c0 + 0.5f * rest;
        out[r*3 + 1] = c1 + 0.5f * rest;
        out[r*3 + 2] = c2 + 0.5f * rest;
        out[3*N_RAYS + r] = dist + 5.f * rest;
        out[4*N_RAYS + r] = opac;
    }
}

extern "C" void kernel_launch(void* const* d_in, const int* in_sizes, int n_in,
                              void* d_out, int out_size, void* d_ws, size_t ws_size,
                              hipStream_t stream) {
    const float* rays_o   = (const float*)d_in[0];
    const float* rays_d   = (const float*)d_in[1];
    const float* t_starts = (const float*)d_in[2];
    const float* t_ends   = (const float*)d_in[3];
    const int*   ray_idx  = (const int*)  d_in[4];
    const float* Wd1 = (const float*)d_in[5];  const float* bd1 = (const float*)d_in[6];
    const float* Wd2 = (const float*)d_in[7];  const float* bd2 = (const float*)d_in[8];
    const float* Wd3 = (const float*)d_in[9];  const float* bd3 = (const float*)d_in[10];
    const float* Wr1 = (const float*)d_in[11]; const float* br1 = (const float*)d_in[12];
    const float* Wr2 = (const float*)d_in[13]; const float* br2 = (const float*)d_in[14];
    const float* Wr3 = (const float*)d_in[15]; const float* br3 = (const float*)d_in[16];

    float4* ws4    = (float4*)d_ws;                    // 16 MB AoS {r,g,b,sd}
    float*  ws_mid = (float*)(ws4 + N_SAMP);           // 4 MB mid plane
    char*   p      = (char*)(ws_mid + N_SAMP);
    int*    startb  = (int*)p;                         // (N_RAYS+1)*4 B
    uint4*  fragbuf = (uint4*)(p + (((N_RAYS+1)*4 + 255) & ~255));
    float4* biasbuf = (float4*)(fragbuf + 2*FRAG_SLOTS*64);
    float*  out     = (float*)d_out;

    hipLaunchKernelGGL(prep_frags, dim3(8), dim3(256), 0, stream,
                       Wd1, bd1, Wd2, bd2, Wd3, bd3,
                       Wr1, br1, Wr2, br2, Wr3, br3, fragbuf, biasbuf);

    hipLaunchKernelGGL(pass_a, dim3(BLK_A), dim3(256), 0, stream,
                       rays_o, rays_d, t_starts, t_ends, ray_idx,
                       fragbuf, biasbuf, bd3, br3, ws4, ws_mid, startb);

    hipLaunchKernelGGL(pass_b, dim3((N_RAYS/2 * 64) / 256), dim3(256), 0, stream,
                       ws4, ws_mid, startb, out);
}